// Round 2
// 939.081 us; speedup vs baseline: 1.0683x; 1.0683x over previous
//
#include <hip/hip_runtime.h>

// ---------------------------------------------------------------------------
// ActivatedHeteroLinear: out = LeakyReLU(BN_train(x @ (W1@W2)))
// Biases b1,b2 are annihilated by BatchNorm's mean subtraction.
// Two passes per type (BN needs full-batch stats): pass1 = GEMM + stats,
// pass2 = recompute GEMM + normalize + LeakyReLU.  bf16 MFMA, fp32 accum.
//
// R1 restructure (resubmit after infra failure): persistent grid-stride waves.
//  - W (fused, bf16) is pre-arranged in MFMA-fragment order by the fuse
//    kernel, staged into LDS ONCE per block (single __syncthreads, LDS
//    read-only afterwards -> no barriers in the streaming loop).
//  - X streams global->VGPR directly (float4 pairs == exact A-fragment
//    footprint, each element read once), converted to bf16 in registers.
//  - Stats accumulate in registers across all tiles of a wave; one
//    shuffle+LDS+atomic reduction per block at kernel end.
// ---------------------------------------------------------------------------

typedef __attribute__((ext_vector_type(8))) short bf16x8;   // 8 bf16 in 4 VGPRs
typedef __attribute__((ext_vector_type(4))) float f32x4;

#define NBUF 128   // replicated atomic stat buffers (contention spreading)
#define GRID 1024  // persistent blocks (4/CU)

// workspace layout (float offsets)
#define WT_U_OFF    0                       // 16x64x8 bf16 frags = 4096 floats
#define WT_I_OFF    4096                    // 32x64x8 bf16 frags = 8192 floats
#define SUM_U_OFF   12288                   // NBUF*128 each
#define SQ_U_OFF    (12288 + 1*NBUF*128)
#define SUM_I_OFF   (12288 + 2*NBUF*128)
#define SQ_I_OFF    (12288 + 3*NBUF*128)
#define SCALE_U_OFF (12288 + 4*NBUF*128)
#define SHIFT_U_OFF (SCALE_U_OFF + 128)
#define SCALE_I_OFF (SCALE_U_OFF + 256)
#define SHIFT_I_OFF (SCALE_U_OFF + 384)

__device__ inline unsigned short f2bf(float f) {
  union { float f; unsigned u; } v; v.f = f;
  return (unsigned short)((v.u + 0x7fffu + ((v.u >> 16) & 1u)) >> 16);  // RNE
}

__device__ inline bf16x8 cvt8(const float4 a, const float4 b) {
  bf16x8 r;
  r[0] = (short)f2bf(a.x); r[1] = (short)f2bf(a.y);
  r[2] = (short)f2bf(a.z); r[3] = (short)f2bf(a.w);
  r[4] = (short)f2bf(b.x); r[5] = (short)f2bf(b.y);
  r[6] = (short)f2bf(b.z); r[7] = (short)f2bf(b.w);
  return r;
}

// K0: zero stat buffers + compute fused weights Wt[c][k] = sum_j W1[k][j]*W2[j][c],
// stored in MFMA B-fragment order:
//   frag f = t*(K/32)+ks holds B[k=ks*32+quad*8+j][n=t*16+l16] at
//   element ((f*64 + quad*16 + l16)*8 + j)  -> GEMM ds_read is lane-linear.
__global__ void fuse_zero_kernel(const float* __restrict__ W1u, const float* __restrict__ W2u,
                                 const float* __restrict__ W1i, const float* __restrict__ W2i,
                                 float* __restrict__ ws) {
  const int b = blockIdx.x;   // 192 blocks: 0..63 user-k, 64..191 item-k
  const int c = threadIdx.x;  // 128 threads = output channel
  const int tid = b * 128 + c;
  for (int i = tid; i < 4 * NBUF * 128; i += 192 * 128) ws[SUM_U_OFF + i] = 0.f;

  const float* W1; const float* W2; int k; unsigned short* wt; int K;
  if (b < 64) { W1 = W1u; W2 = W2u; k = b;      wt = (unsigned short*)(ws + WT_U_OFF); K = 64; }
  else        { W1 = W1i; W2 = W2i; k = b - 64; wt = (unsigned short*)(ws + WT_I_OFF); K = 128; }
  float s = 0.f;
  for (int j = 0; j < 256; ++j) s += W1[k * 256 + j] * W2[j * 128 + c];
  const int t = c >> 4, l16 = c & 15;
  const int ks = k >> 5, quad = (k >> 3) & 3, j = k & 7;
  const int f = t * (K / 32) + ks;
  wt[(f * 64 + quad * 16 + l16) * 8 + j] = f2bf(s);
}

// K3: reduce replicated stats -> scale/shift per channel per type
__global__ void finalize_kernel(float* __restrict__ ws,
                                const float* __restrict__ gU, const float* __restrict__ bU,
                                const float* __restrict__ gI, const float* __restrict__ bI,
                                float invNu, float invNi) {
  const int typ = blockIdx.x;   // 0=user 1=item
  const int c = threadIdx.x;    // 128
  const float* sums = ws + (typ ? SUM_I_OFF : SUM_U_OFF);
  const float* sqs  = ws + (typ ? SQ_I_OFF  : SQ_U_OFF);
  const float invN  = typ ? invNi : invNu;
  float s = 0.f, q = 0.f;
  for (int b2 = 0; b2 < NBUF; ++b2) { s += sums[b2 * 128 + c]; q += sqs[b2 * 128 + c]; }
  const float mean = s * invN;
  const float var  = q * invN - mean * mean;   // biased variance (matches ref)
  const float* g  = typ ? gI : gU;
  const float* be = typ ? bI : bU;
  const float sc = g[c] * rsqrtf(var + 1e-5f);
  const float sh = be[c] - mean * sc;
  ws[(typ ? SCALE_I_OFF : SCALE_U_OFF) + c] = sc;
  ws[(typ ? SHIFT_I_OFF : SHIFT_U_OFF) + c] = sh;
}

// Main GEMM: persistent blocks of 256 thr (4 waves). Each wave grid-strides
// over 16-row tiles; per tile: 8 cols-tiles x (K/32) k-steps of
// mfma_f32_16x16x32_bf16.  W lives in LDS (fragment order, conflict-free
// lane-linear ds_read_b128, loaded once).  X is loaded straight from global.
template <int K, bool STATS>
__global__ __launch_bounds__(256) void hgemm_kernel(
    const float* __restrict__ x,                 // [N, K] fp32
    const unsigned short* __restrict__ wt,       // fragment-ordered bf16 bits
    float* __restrict__ sum_buf, float* __restrict__ sq_buf,     // STATS
    const float* __restrict__ scale, const float* __restrict__ shift,
    float* __restrict__ out,                     // [N, 128] fp32
    int nTiles)                                  // N/16
{
  constexpr int NFRAG = 8 * (K / 32);
  __shared__ __align__(16) unsigned short wsh[NFRAG * 64 * 8];  // 16KB / 32KB
  __shared__ float bsum[128];
  __shared__ float bsq[128];

  const int tid = threadIdx.x;

  // stage W frags (linear copy, already fragment-ordered)
  {
    const uint4* src = (const uint4*)wt;
    uint4* dst = (uint4*)wsh;
    constexpr int CH = NFRAG * 64;              // 16B chunks
    for (int i = tid; i < CH; i += 256) dst[i] = src[i];
  }
  if (STATS && tid < 128) { bsum[tid] = 0.f; bsq[tid] = 0.f; }
  __syncthreads();   // the ONLY barrier before the end-of-kernel reduction

  const int lane = tid & 63;
  const int wave = tid >> 6;
  const int l16  = lane & 15;
  const int quad = lane >> 4;
  const unsigned short* wbase = &wsh[lane * 8];  // + f*512 shorts per frag

  float sc[8], sh[8];
  if (!STATS) {
#pragma unroll
    for (int t = 0; t < 8; ++t) { sc[t] = scale[t * 16 + l16]; sh[t] = shift[t * 16 + l16]; }
  }
  float st1[8], st2[8];
  if (STATS) {
#pragma unroll
    for (int t = 0; t < 8; ++t) { st1[t] = 0.f; st2[t] = 0.f; }
  }

  const int gwave   = blockIdx.x * 4 + wave;
  const int wstride = gridDim.x * 4;

  for (int tile = gwave; tile < nTiles; tile += wstride) {
    const float* xr = x + (long long)(tile * 16 + l16) * K + quad * 8;
    // A fragments: lane (l16,quad) holds A[m=l16][k=ks*32+quad*8+j], each
    // element loaded exactly once, 128B contiguous per row per k-step.
    float4 af0[K / 32], af1[K / 32];
#pragma unroll
    for (int ks = 0; ks < K / 32; ++ks) {
      af0[ks] = *(const float4*)(xr + ks * 32);
      af1[ks] = *(const float4*)(xr + ks * 32 + 4);
    }

    f32x4 acc[8];
#pragma unroll
    for (int t = 0; t < 8; ++t) acc[t] = (f32x4){0.f, 0.f, 0.f, 0.f};

#pragma unroll
    for (int ks = 0; ks < K / 32; ++ks) {
      const bf16x8 a = cvt8(af0[ks], af1[ks]);
#pragma unroll
      for (int t = 0; t < 8; ++t) {
        const bf16x8 b = *(const bf16x8*)(wbase + (t * (K / 32) + ks) * 512);
        acc[t] = __builtin_amdgcn_mfma_f32_16x16x32_bf16(a, b, acc[t], 0, 0, 0);
      }
    }

    if (STATS) {
      // C layout: col = t*16 + l16, rows = quad*4 + i.
#pragma unroll
      for (int t = 0; t < 8; ++t) {
        st1[t] += acc[t][0] + acc[t][1] + acc[t][2] + acc[t][3];
        st2[t] += acc[t][0] * acc[t][0] + acc[t][1] * acc[t][1] +
                  acc[t][2] * acc[t][2] + acc[t][3] * acc[t][3];
      }
    } else {
#pragma unroll
      for (int t = 0; t < 8; ++t) {
        const int c = t * 16 + l16;
#pragma unroll
        for (int i = 0; i < 4; ++i) {
          const long long r = (long long)tile * 16 + quad * 4 + i;
          float v = acc[t][i] * sc[t] + sh[t];
          v = (v >= 0.f) ? v : 0.01f * v;
          out[r * 128 + c] = v;
        }
      }
    }
  }

  if (STATS) {
    // quads of a column share c: reduce across lanes 16/32 apart, then one
    // LDS-atomic per column per wave, then one global atomic per column/block.
#pragma unroll
    for (int t = 0; t < 8; ++t) {
      float s1 = st1[t], s2 = st2[t];
      s1 += __shfl_xor(s1, 16, 64);  s2 += __shfl_xor(s2, 16, 64);
      s1 += __shfl_xor(s1, 32, 64);  s2 += __shfl_xor(s2, 32, 64);
      if (quad == 0) {
        atomicAdd(&bsum[t * 16 + l16], s1);
        atomicAdd(&bsq[t * 16 + l16], s2);
      }
    }
    __syncthreads();
    if (tid < 128) {
      const int buf = blockIdx.x & (NBUF - 1);
      atomicAdd(&sum_buf[buf * 128 + tid], bsum[tid]);
      atomicAdd(&sq_buf[buf * 128 + tid], bsq[tid]);
    }
  }
}

extern "C" void kernel_launch(void* const* d_in, const int* in_sizes, int n_in,
                              void* d_out, int out_size, void* d_ws, size_t ws_size,
                              hipStream_t stream) {
  const float* xu  = (const float*)d_in[0];
  const float* xi  = (const float*)d_in[1];
  const float* W1u = (const float*)d_in[2];
  const float* W1i = (const float*)d_in[4];
  const float* W2u = (const float*)d_in[6];
  const float* W2i = (const float*)d_in[8];
  const float* gU  = (const float*)d_in[10];
  const float* bU  = (const float*)d_in[11];
  const float* gI  = (const float*)d_in[12];
  const float* bI  = (const float*)d_in[13];
  float* ws = (float*)d_ws;

  const int Nu = in_sizes[0] / 64;    // 400000 rows
  const int Ni = in_sizes[1] / 128;   // 600000 rows
  float* outU = (float*)d_out;
  float* outI = outU + (long long)Nu * 128;

  hipLaunchKernelGGL(fuse_zero_kernel, dim3(192), dim3(128), 0, stream,
                     W1u, W2u, W1i, W2i, ws);
  hipLaunchKernelGGL((hgemm_kernel<64, true>), dim3(GRID), dim3(256), 0, stream,
                     xu, (const unsigned short*)(ws + WT_U_OFF),
                     ws + SUM_U_OFF, ws + SQ_U_OFF, nullptr, nullptr, nullptr, Nu / 16);
  hipLaunchKernelGGL((hgemm_kernel<128, true>), dim3(GRID), dim3(256), 0, stream,
                     xi, (const unsigned short*)(ws + WT_I_OFF),
                     ws + SUM_I_OFF, ws + SQ_I_OFF, nullptr, nullptr, nullptr, Ni / 16);
  hipLaunchKernelGGL(finalize_kernel, dim3(2), dim3(128), 0, stream,
                     ws, gU, bU, gI, bI, 1.f / (float)Nu, 1.f / (float)Ni);
  hipLaunchKernelGGL((hgemm_kernel<64, false>), dim3(GRID), dim3(256), 0, stream,
                     xu, (const unsigned short*)(ws + WT_U_OFF), nullptr, nullptr,
                     ws + SCALE_U_OFF, ws + SHIFT_U_OFF, outU, Nu / 16);
  hipLaunchKernelGGL((hgemm_kernel<128, false>), dim3(GRID), dim3(256), 0, stream,
                     xi, (const unsigned short*)(ws + WT_I_OFF), nullptr, nullptr,
                     ws + SCALE_I_OFF, ws + SHIFT_I_OFF, outI, Ni / 16);
}